// Round 4
// baseline (219.333 us; speedup 1.0000x reference)
//
#include <hip/hip_runtime.h>

// HierarchicalMultinomialRegression: fused fixed-effects GEMV + per-row AR(1)
// recurrence replay + gather. Never materializes u (B,L,T,Km1).
//
// Round 4 changes (issue-cost / latency, traffic unchanged):
//  - M (wave-uniform 7x7) hoisted to SGPRs via readfirstlane: removes
//    49 ds_read_b32 per recurrence step (931/thread) -> recurrence issue
//    cost ~halves.
//  - eps loaded as float4 chunks of 4 timesteps (7 dwordx4, 16B-aligned),
//    double-buffered A/B with fully static indexing: 140 scalar loads ->
//    <=35 vector loads, 7-deep MLP, chunk0 prefetched under the GEMV.
//  - beta read as ds_read_b128 (28 contiguous floats per 4 X-cols,
//    broadcast): 448 -> 112 LDS instrs. X loaded 8 float4 per half-pass.
//
// Inputs (setup_inputs dict order):
//  0: X (N,64) f32   1: beta (64,7) f32   2: raw_rho (7,7) f32
//  3: raw_chol (7,7,7) f32 (Km1,L,L)      4: eps (B,7,20,7) f32
//  5: batter_ids (N,) i32  6: league_ids  7: season_ids
// Output: logits (N,8) then eps_sample (N,7), concatenated flat, f32.

#define NF 64
#define LDIM 7
#define TDIM 20
#define KM1 7
#define BLOCK 256
#define PAD 9   // LDS row stride (floats); 9 coprime to 32 banks

__device__ __forceinline__ float comp4(const float4& v, int c) {
    switch (c & 3) { case 0: return v.x; case 1: return v.y;
                     case 2: return v.z; default: return v.w; }
}

// load chunk C (timesteps 4C..4C+3) of this row: 7 float4, 16B-aligned
#define LOADC(BUF, C) { \
    _Pragma("unroll") \
    for (int q = 0; q < 7; ++q) BUF[q] = e4[(C) * 7 + q]; \
}

// process timesteps 4C..4C+3 from BUF (all indices compile-time constant)
#define PROC(BUF, C) { \
    _Pragma("unroll") \
    for (int i = 0; i < 4; ++i) { \
        const int s = 4 * (C) + i; \
        if (s <= t) { \
            float e[KM1]; \
            _Pragma("unroll") \
            for (int k = 0; k < KM1; ++k) \
                e[k] = comp4(BUF[(i * KM1 + k) >> 2], i * KM1 + k); \
            if (s >= 1) {  /* compile-time prune at C==0,i==0 */ \
                float nz[KM1]; \
                _Pragma("unroll") \
                for (int j = 0; j < KM1; ++j) { \
                    float m = 0.f; \
                    _Pragma("unroll") \
                    for (int k = 0; k < KM1; ++k) m += e[k] * mm[k * KM1 + j]; \
                    nz[j] = m; \
                } \
                _Pragma("unroll") \
                for (int j = 0; j < KM1; ++j) u[j] = rho_l[j] * u[j] + nz[j]; \
            } \
            if (s == t) { \
                _Pragma("unroll") \
                for (int k = 0; k < KM1; ++k) s_es[tid * PAD + k] = e[k]; \
            } \
        } \
    } \
}

__global__ __launch_bounds__(BLOCK, 3) void hmr_kernel(
    const float* __restrict__ X,
    const float* __restrict__ beta,
    const float* __restrict__ raw_rho,
    const float* __restrict__ raw_chol,
    const float* __restrict__ eps,
    const int* __restrict__ batter_ids,
    const int* __restrict__ league_ids,
    const int* __restrict__ season_ids,
    float* __restrict__ out,
    int n_total)
{
    __shared__ float s_beta[NF * KM1];       // beta[j][k]
    __shared__ float s_rho[LDIM][KM1];       // tanh(raw_rho)
    __shared__ float s_sd[LDIM][KM1];        // scaling * diag(chol)
    __shared__ float s_M[KM1 * KM1];         // M[k][j] flattened
    __shared__ float s_log[BLOCK * PAD];     // staged logits rows
    __shared__ float s_es[BLOCK * PAD];      // staged eps_sample rows

    const int tid = threadIdx.x;

    for (int i = tid; i < NF * KM1; i += BLOCK) s_beta[i] = beta[i];

    if (tid < LDIM * KM1) {
        const int l = tid / KM1, k = tid % KM1;
        const float r = tanhf(raw_rho[l * KM1 + k]);
        s_rho[l][k] = r;
        const float scal = 1.0f / sqrtf(1.0f - r * r);
        s_sd[l][k] = scal * raw_chol[k * (LDIM * LDIM) + l * LDIM + l];
        const int k2 = l, j = k;             // reuse 7x7 index space for M
        float m = 0.f;
        #pragma unroll
        for (int i2 = 0; i2 < LDIM; ++i2)
            m += raw_chol[k2 * (LDIM * LDIM) + i2 * LDIM + j];
        s_M[k2 * KM1 + j] = m;
    }
    __syncthreads();

    const int bstart = blockIdx.x * BLOCK;
    const int n = bstart + tid;

    if (n < n_total) {
        const int b = batter_ids[n];
        const int l = league_ids[n];
        const int t = season_ids[n];

        // ---- hoist wave-uniform M into SGPRs ----
        float mm[KM1 * KM1];
        #pragma unroll
        for (int q = 0; q < KM1 * KM1; ++q)
            mm[q] = __int_as_float(
                __builtin_amdgcn_readfirstlane(__float_as_int(s_M[q])));

        // ---- prefetch eps chunk 0 (hides under GEMV) ----
        const float4* __restrict__ e4 =
            reinterpret_cast<const float4*>(eps) + (long)(b * LDIM + l) * 35;
        float4 A[7], B[7];
        LOADC(A, 0);

        // ---- fixed effects: acc[k] = sum_j X[n,j]*beta[j,k] ----
        float acc[KM1];
        #pragma unroll
        for (int k = 0; k < KM1; ++k) acc[k] = 0.f;

        const float4* __restrict__ xrow =
            reinterpret_cast<const float4*>(X + (long)n * NF);

        #pragma unroll
        for (int half = 0; half < 2; ++half) {
            float4 xr[8];
            #pragma unroll
            for (int q = 0; q < 8; ++q) xr[q] = xrow[half * 8 + q];
            #pragma unroll
            for (int j4 = 0; j4 < 8; ++j4) {
                const int g = half * 8 + j4;     // group of 4 X-columns
                const float4* bb =
                    reinterpret_cast<const float4*>(&s_beta[g * 28]);
                float4 b4[7];
                #pragma unroll
                for (int q = 0; q < 7; ++q) b4[q] = bb[q];  // ds_read_b128 x7
                #pragma unroll
                for (int jj = 0; jj < 4; ++jj) {
                    const float xv = comp4(xr[j4], jj);
                    #pragma unroll
                    for (int k = 0; k < KM1; ++k) {
                        const int fi = jj * KM1 + k;
                        acc[k] += xv * comp4(b4[fi >> 2], fi);
                    }
                }
            }
        }

        // ---- AR(1) recurrence, chunked + double-buffered ----
        float rho_l[KM1], u[KM1];
        #pragma unroll
        for (int k = 0; k < KM1; ++k) {
            rho_l[k] = s_rho[l][k];
            u[k] = s_sd[l][k] * comp4(A[k >> 2], k);
        }

        const int nch = (t >> 2) + 1;  // chunks needed; step t never straddles

        if (nch > 1) LOADC(B, 1);
        PROC(A, 0);
        if (nch > 1) {
            if (nch > 2) LOADC(A, 2);
            PROC(B, 1);
            if (nch > 2) {
                if (nch > 3) LOADC(B, 3);
                PROC(A, 2);
                if (nch > 3) {
                    if (nch > 4) LOADC(A, 4);
                    PROC(B, 3);
                    if (nch > 4) { PROC(A, 4); }
                }
            }
        }

        // ---- stage logits row ----
        s_log[tid * PAD + 0] = 0.f;
        #pragma unroll
        for (int k = 0; k < KM1; ++k) s_log[tid * PAD + 1 + k] = acc[k] + u[k];
    }
    __syncthreads();

    // ---- dense, fully-coalesced global writes ----
    const int rows = min(BLOCK, n_total - bstart);

    {   // logits region: rows*8 contiguous floats
        float* __restrict__ dst = out + (long)bstart * 8;
        const int cnt = rows * 8;
        for (int i = tid; i < cnt; i += BLOCK) {
            const int r = i >> 3, c = i & 7;
            dst[i] = s_log[r * PAD + c];
        }
    }
    {   // eps_sample region: rows*7 contiguous floats
        float* __restrict__ dst = out + (long)n_total * 8 + (long)bstart * KM1;
        const int cnt = rows * KM1;
        for (int i = tid; i < cnt; i += BLOCK) {
            const int r = i / KM1, c = i - r * KM1;
            dst[i] = s_es[r * PAD + c];
        }
    }
}

extern "C" void kernel_launch(void* const* d_in, const int* in_sizes, int n_in,
                              void* d_out, int out_size, void* d_ws, size_t ws_size,
                              hipStream_t stream)
{
    const float* X        = (const float*)d_in[0];
    const float* beta     = (const float*)d_in[1];
    const float* raw_rho  = (const float*)d_in[2];
    const float* raw_chol = (const float*)d_in[3];
    const float* eps      = (const float*)d_in[4];
    const int* batter_ids = (const int*)d_in[5];
    const int* league_ids = (const int*)d_in[6];
    const int* season_ids = (const int*)d_in[7];
    float* out = (float*)d_out;

    const int n_total = in_sizes[5];  // N = 200000
    const int grid = (n_total + BLOCK - 1) / BLOCK;

    hmr_kernel<<<grid, BLOCK, 0, stream>>>(X, beta, raw_rho, raw_chol, eps,
                                           batter_ids, league_ids, season_ids,
                                           out, n_total);
}

// Round 5
// 59.218 us; speedup vs baseline: 3.7038x; 3.7038x over previous
//
#include <hip/hip_runtime.h>

// HierarchicalMultinomialRegression: fused fixed-effects GEMV + per-row AR(1)
// recurrence replay + gather. Never materializes u (B,L,T,Km1).
//
// Round 5 = round-3 skeleton (47.5us, no spills) + bounded LDS-issue cuts.
// Round 4's lesson: the same ideas with 116+ simultaneously-live buffer regs
// spilled to scratch (WRITE 354MB, occupancy 0.4%, 219us). Here transient
// state is capped (~30 regs):
//  - beta read as broadcast ds_read_b128 (28 contiguous floats per 4-col
//    group, 112B-aligned): 448 -> 112 LDS instrs/thread. unroll 2 only.
//  - M stored transposed+padded s_Mt[7][8]: nz[j] row read = 2 ds_read_b128
//    (broadcast): 49 -> 14 LDS instrs per recurrence step (931 -> 266).
//  - eps software-pipelined one step ahead (7 regs, static indexing) so the
//    gather latency hides under the 98-FLOP step body.
//
// Inputs (setup_inputs dict order):
//  0: X (N,64) f32   1: beta (64,7) f32   2: raw_rho (7,7) f32
//  3: raw_chol (7,7,7) f32 (Km1,L,L)      4: eps (B,7,20,7) f32
//  5: batter_ids (N,) i32  6: league_ids  7: season_ids
// Output: logits (N,8) then eps_sample (N,7), concatenated flat, f32.

#define NF 64
#define LDIM 7
#define TDIM 20
#define KM1 7
#define BLOCK 256
#define PAD 9   // LDS output-row stride (floats); 9 coprime to 32 banks

__device__ __forceinline__ float comp4(const float4& v, int c) {
    switch (c & 3) { case 0: return v.x; case 1: return v.y;
                     case 2: return v.z; default: return v.w; }
}

__global__ __launch_bounds__(BLOCK, 3) void hmr_kernel(
    const float* __restrict__ X,
    const float* __restrict__ beta,
    const float* __restrict__ raw_rho,
    const float* __restrict__ raw_chol,
    const float* __restrict__ eps,
    const int* __restrict__ batter_ids,
    const int* __restrict__ league_ids,
    const int* __restrict__ season_ids,
    float* __restrict__ out,
    int n_total)
{
    __shared__ float s_beta[NF * KM1];        // beta[j][k], row-major
    __shared__ float s_rho[LDIM][KM1];        // tanh(raw_rho)
    __shared__ float s_sd[LDIM][KM1];         // scaling * diag(chol)
    __shared__ __align__(16) float s_Mt[KM1][8];  // Mt[j][k] = M[k][j], padded
    __shared__ float s_log[BLOCK * PAD];      // staged logits rows
    __shared__ float s_es[BLOCK * PAD];       // staged eps_sample rows

    const int tid = threadIdx.x;

    for (int i = tid; i < NF * KM1; i += BLOCK) s_beta[i] = beta[i];

    if (tid < LDIM * KM1) {
        const int l = tid / KM1, k = tid % KM1;
        const float r = tanhf(raw_rho[l * KM1 + k]);
        s_rho[l][k] = r;
        const float scal = 1.0f / sqrtf(1.0f - r * r);
        s_sd[l][k] = scal * raw_chol[k * (LDIM * LDIM) + l * LDIM + l];
        // reuse the 7x7 index space: Mt[j][k2] = sum_i chol[k2][i][j]
        const int k2 = l, j = k;
        float m = 0.f;
        #pragma unroll
        for (int i2 = 0; i2 < LDIM; ++i2)
            m += raw_chol[k2 * (LDIM * LDIM) + i2 * LDIM + j];
        s_Mt[j][k2] = m;
    }
    if (tid < KM1) s_Mt[tid][7] = 0.f;        // zero the pad lane
    __syncthreads();

    const int bstart = blockIdx.x * BLOCK;
    const int n = bstart + tid;

    if (n < n_total) {
        const int b = batter_ids[n];
        const int l = league_ids[n];
        const int t = season_ids[n];

        // ---- fixed effects: acc[k] = sum_j X[n,j]*beta[j,k] ----
        float acc[KM1];
        #pragma unroll
        for (int k = 0; k < KM1; ++k) acc[k] = 0.f;

        const float4* __restrict__ xrow =
            reinterpret_cast<const float4*>(X + (long)n * NF);

        #pragma unroll 2
        for (int j4 = 0; j4 < NF / 4; ++j4) {
            const float4 x = xrow[j4];
            const float4* bb =
                reinterpret_cast<const float4*>(&s_beta[j4 * 28]);
            float4 b4[7];
            #pragma unroll
            for (int q = 0; q < 7; ++q) b4[q] = bb[q];   // broadcast b128
            #pragma unroll
            for (int jj = 0; jj < 4; ++jj) {
                const float xv = comp4(x, jj);
                #pragma unroll
                for (int k = 0; k < KM1; ++k) {
                    const int fi = jj * KM1 + k;
                    acc[k] += xv * comp4(b4[fi >> 2], fi);
                }
            }
        }

        // ---- AR(1) recurrence replay up to t ----
        const float* __restrict__ erow =
            eps + ((long)b * LDIM + l) * (TDIM * KM1);

        float last_e[KM1], u[KM1], rho_l[KM1];
        #pragma unroll
        for (int k = 0; k < KM1; ++k) {
            last_e[k] = erow[k];
            rho_l[k] = s_rho[l][k];
            u[k] = s_sd[l][k] * last_e[k];
        }

        if (t > 0) {
            float e[KM1];
            #pragma unroll
            for (int k = 0; k < KM1; ++k) e[k] = erow[KM1 + k];  // step 1

            for (int s = 1;; ++s) {
                const bool more = (s < t);
                float en[KM1];
                if (more) {
                    #pragma unroll
                    for (int k = 0; k < KM1; ++k)
                        en[k] = erow[(s + 1) * KM1 + k];
                }
                // nz[j] = dot(e, Mt_row_j): 2 broadcast b128 per row
                float nz[KM1];
                #pragma unroll
                for (int j = 0; j < KM1; ++j) {
                    const float4* mt =
                        reinterpret_cast<const float4*>(&s_Mt[j][0]);
                    const float4 m0 = mt[0], m1 = mt[1];
                    nz[j] = e[0] * m0.x + e[1] * m0.y + e[2] * m0.z +
                            e[3] * m0.w + e[4] * m1.x + e[5] * m1.y +
                            e[6] * m1.z;
                }
                #pragma unroll
                for (int j = 0; j < KM1; ++j)
                    u[j] = rho_l[j] * u[j] + nz[j];

                if (!more) {
                    #pragma unroll
                    for (int k = 0; k < KM1; ++k) last_e[k] = e[k];
                    break;
                }
                #pragma unroll
                for (int k = 0; k < KM1; ++k) e[k] = en[k];
            }
        }

        // ---- stage outputs in padded LDS rows (conflict-free) ----
        s_log[tid * PAD + 0] = 0.f;
        #pragma unroll
        for (int k = 0; k < KM1; ++k) s_log[tid * PAD + 1 + k] = acc[k] + u[k];
        #pragma unroll
        for (int k = 0; k < KM1; ++k) s_es[tid * PAD + k] = last_e[k];
    }
    __syncthreads();

    // ---- dense, fully-coalesced global writes ----
    const int rows = min(BLOCK, n_total - bstart);

    {   // logits region: rows*8 contiguous floats
        float* __restrict__ dst = out + (long)bstart * 8;
        const int cnt = rows * 8;
        for (int i = tid; i < cnt; i += BLOCK) {
            const int r = i >> 3, c = i & 7;
            dst[i] = s_log[r * PAD + c];
        }
    }
    {   // eps_sample region: rows*7 contiguous floats
        float* __restrict__ dst = out + (long)n_total * 8 + (long)bstart * KM1;
        const int cnt = rows * KM1;
        for (int i = tid; i < cnt; i += BLOCK) {
            const int r = i / KM1, c = i - r * KM1;
            dst[i] = s_es[r * PAD + c];
        }
    }
}

extern "C" void kernel_launch(void* const* d_in, const int* in_sizes, int n_in,
                              void* d_out, int out_size, void* d_ws, size_t ws_size,
                              hipStream_t stream)
{
    const float* X        = (const float*)d_in[0];
    const float* beta     = (const float*)d_in[1];
    const float* raw_rho  = (const float*)d_in[2];
    const float* raw_chol = (const float*)d_in[3];
    const float* eps      = (const float*)d_in[4];
    const int* batter_ids = (const int*)d_in[5];
    const int* league_ids = (const int*)d_in[6];
    const int* season_ids = (const int*)d_in[7];
    float* out = (float*)d_out;

    const int n_total = in_sizes[5];  // N = 200000
    const int grid = (n_total + BLOCK - 1) / BLOCK;

    hmr_kernel<<<grid, BLOCK, 0, stream>>>(X, beta, raw_rho, raw_chol, eps,
                                           batter_ids, league_ids, season_ids,
                                           out, n_total);
}

// Round 6
// 52.403 us; speedup vs baseline: 4.1855x; 1.1300x over previous
//
#include <hip/hip_runtime.h>

// HierarchicalMultinomialRegression: channel-parallel fused kernel.
// One 8-lane group per row n; lane k owns output channel k (lane 7 = the
// zeros column of logits). Never materializes u (B,L,T,Km1).
//
// Round 6 redesign rationale:
//  - Round-3 structure (1 thread/row) was TLP-starved: 3128 waves total
//    (12/CU, one cohort) and ~115+ VGPRs (compiler hoists the 7x7 M into
//    regs) -> ~3 waves/SIMD -> the 19-step divergent eps-gather chain
//    (~700cy/step) is exposed. Round 5 proved cutting "LDS issue" was
//    attacking a non-bottleneck (M was already register-resident).
//  - Here: lane j keeps only M COLUMN j (7 regs) -> ~45 VGPR -> 8 waves/SIMD;
//    25000 waves (~98/CU) of TLP; recurrence step = 1 coalesced load +
//    7 __shfl(width=8) + ~9 VALU, predicated to a wave-uniform tmax
//    (no divergent branches); outputs coalesce with no LDS staging.
//
// Inputs (setup_inputs dict order):
//  0: X (N,64) f32   1: beta (64,7) f32   2: raw_rho (7,7) f32
//  3: raw_chol (7,7,7) f32 (Km1,L,L)      4: eps (B,7,20,7) f32
//  5: batter_ids (N,) i32  6: league_ids  7: season_ids
// Output: logits (N,8) then eps_sample (N,7), concatenated flat, f32.

#define NF 64
#define LDIM 7
#define TDIM 20
#define KM1 7
#define BLOCK 256
#define RPB (BLOCK / 8)   // rows per block = 32

__device__ __forceinline__ float comp4(const float4& v, int c) {
    switch (c & 3) { case 0: return v.x; case 1: return v.y;
                     case 2: return v.z; default: return v.w; }
}

__global__ __launch_bounds__(BLOCK, 8) void hmr_kernel(
    const float* __restrict__ X,
    const float* __restrict__ beta,
    const float* __restrict__ raw_rho,
    const float* __restrict__ raw_chol,
    const float* __restrict__ eps,
    const int* __restrict__ batter_ids,
    const int* __restrict__ league_ids,
    const int* __restrict__ season_ids,
    float* __restrict__ out,
    int n_total)
{
    // small constants in LDS (padded so lane 7's garbage reads stay in-bounds)
    __shared__ float s_beta[NF * KM1 + 8];   // beta[j][k]
    __shared__ float s_rho[56];              // tanh(raw_rho)[l][k]
    __shared__ float s_sd[56];               // scaling*diag [l][k]
    __shared__ float s_M[56];                // M[k][j] row-major

    const int tid = threadIdx.x;

    for (int i = tid; i < NF * KM1; i += BLOCK) s_beta[i] = beta[i];
    if (tid < 8) s_beta[NF * KM1 + tid] = 0.f;

    if (tid < LDIM * KM1) {
        const int l = tid / KM1, k = tid % KM1;
        const float r = tanhf(raw_rho[l * KM1 + k]);
        s_rho[tid] = r;
        s_sd[tid] = (1.0f / sqrtf(1.0f - r * r)) *
                    raw_chol[k * (LDIM * LDIM) + l * LDIM + l];
        const int k2 = l, j = k;             // reuse 7x7 index space for M
        float m = 0.f;
        #pragma unroll
        for (int i2 = 0; i2 < LDIM; ++i2)
            m += raw_chol[k2 * (LDIM * LDIM) + i2 * LDIM + j];
        s_M[k2 * KM1 + j] = m;
    } else if (tid < 56) {
        s_rho[tid] = 0.f; s_sd[tid] = 0.f; s_M[tid] = 0.f;
    }
    __syncthreads();

    const int r = tid >> 3;          // row within block
    const int klane = tid & 7;       // channel (7 = zeros column)
    const int k_ld = klane < 6 ? klane : 6;  // clamped for safe loads
    int n = blockIdx.x * RPB + r;
    const bool valid = (n < n_total);
    if (!valid) n = n_total - 1;     // clamp loads; stores predicated below

    const int b = batter_ids[n];
    const int l = league_ids[n];
    const int t = season_ids[n];

    // ---- per-lane constants ----
    float Mcol[KM1];
    #pragma unroll
    for (int kk = 0; kk < KM1; ++kk) Mcol[kk] = s_M[kk * KM1 + klane];
    const float rho = s_rho[l * KM1 + klane];
    const float sd  = s_sd[l * KM1 + klane];

    // ---- fixed effects: acc = sum_j X[n,j] * beta[j,klane] ----
    float acc = 0.f;
    const float4* __restrict__ xrow =
        reinterpret_cast<const float4*>(X + (long)n * NF);
    #pragma unroll 4
    for (int j4 = 0; j4 < NF / 4; ++j4) {
        const float4 x = xrow[j4];
        #pragma unroll
        for (int jj = 0; jj < 4; ++jj)
            acc = fmaf(comp4(x, jj), s_beta[(j4 * 4 + jj) * KM1 + klane], acc);
    }

    // ---- AR(1) recurrence, channel-parallel ----
    const float* __restrict__ erow = eps + ((long)b * LDIM + l) * (TDIM * KM1);

    const float e0 = erow[k_ld];     // own channel, step 0
    float u = sd * e0;
    float last_e = e0;

    // wave-uniform loop bound (branchless divergence handling)
    int tmax = t;
    #pragma unroll
    for (int off = 32; off >= 1; off >>= 1)
        tmax = max(tmax, __shfl_xor(tmax, off));
    tmax = __builtin_amdgcn_readfirstlane(tmax);

    if (tmax > 0) {
        float ecur = erow[KM1 + k_ld];           // step 1, own channel
        for (int s = 1; s <= tmax; ++s) {
            const int snext = (s + 1 < TDIM) ? s + 1 : TDIM - 1;
            const float enext = erow[snext * KM1 + k_ld];  // prefetch
            float nz = 0.f;
            #pragma unroll
            for (int kk = 0; kk < KM1; ++kk)
                nz = fmaf(Mcol[kk], __shfl(ecur, kk, 8), nz);
            u = (s <= t) ? fmaf(rho, u, nz) : u;
            last_e = (s == t) ? ecur : last_e;
            ecur = enext;
        }
    }

    // ---- coalesced writes, no staging ----
    if (valid) {
        // wave covers 64 consecutive dwords of the logits region
        const int col = (klane == 7) ? 0 : klane + 1;
        out[(long)n * 8 + col] = (klane == 7) ? 0.f : (acc + u);
        // eps_sample: contiguous fully-covered 224B span per wave
        if (klane < KM1)
            out[(long)n_total * 8 + (long)n * KM1 + klane] = last_e;
    }
}

extern "C" void kernel_launch(void* const* d_in, const int* in_sizes, int n_in,
                              void* d_out, int out_size, void* d_ws, size_t ws_size,
                              hipStream_t stream)
{
    const float* X        = (const float*)d_in[0];
    const float* beta     = (const float*)d_in[1];
    const float* raw_rho  = (const float*)d_in[2];
    const float* raw_chol = (const float*)d_in[3];
    const float* eps      = (const float*)d_in[4];
    const int* batter_ids = (const int*)d_in[5];
    const int* league_ids = (const int*)d_in[6];
    const int* season_ids = (const int*)d_in[7];
    float* out = (float*)d_out;

    const int n_total = in_sizes[5];  // N = 200000
    const int grid = (n_total + RPB - 1) / RPB;

    hmr_kernel<<<grid, BLOCK, 0, stream>>>(X, beta, raw_rho, raw_chol, eps,
                                           batter_ids, league_ids, season_ids,
                                           out, n_total);
}